// Round 1
// baseline (165.567 us; speedup 1.0000x reference)
//
#include <hip/hip_runtime.h>
#include <hip/hip_bf16.h>

// out[n, d] = x[n, d] * w[d]   (N=200000, D=512, fp32)
// Pure HBM-bound stream: vectorize as float4, grid-stride loop.
// D/4 = 128 float4 per row -> weight float4 index = i & 127.

__global__ __launch_bounds__(256) void colscale_kernel(
    const float4* __restrict__ x4,
    const float4* __restrict__ w4,   // 128 float4 (512 floats), L1/L2 resident
    float4* __restrict__ out4,
    long long n4)                    // total float4 count
{
    long long i = (long long)blockIdx.x * blockDim.x + threadIdx.x;
    long long stride = (long long)gridDim.x * blockDim.x;
    for (; i < n4; i += stride) {
        float4 v = x4[i];
        float4 w = w4[(int)(i & 127)];
        v.x *= w.x;
        v.y *= w.y;
        v.z *= w.z;
        v.w *= w.w;
        out4[i] = v;
    }
}

extern "C" void kernel_launch(void* const* d_in, const int* in_sizes, int n_in,
                              void* d_out, int out_size, void* d_ws, size_t ws_size,
                              hipStream_t stream) {
    const float4* x4 = (const float4*)d_in[0];          // x: [N, D] fp32
    const float4* w4 = (const float4*)d_in[1];          // weight_local: [D, 1] fp32
    float4* out4 = (float4*)d_out;

    long long n4 = (long long)out_size / 4;             // 200000*512/4 = 25.6M

    const int block = 256;
    // Cap grid at ~2048 blocks (256 CU x 8 blocks), grid-stride the rest.
    long long want = (n4 + block - 1) / block;
    int grid = (int)(want < 2048 ? want : 2048);

    colscale_kernel<<<grid, block, 0, stream>>>(x4, w4, out4, n4);
}